// Round 2
// 639.066 us; speedup vs baseline: 1.0049x; 1.0049x over previous
//
#include <hip/hip_runtime.h>

// GraphPoolLayer: per-degree max-pool over gathered neighbor features.
// N = 11 buckets * 50000 rows, D = 128 fp32 features.
// out[row] = max(feat[row], feat[adj[deg][local][0..deg-1]]) elementwise.
//
// R2: nontemporal stores for `out` + nontemporal loads for adjacency.
// (R1 failed to compile: __builtin_nontemporal_store needs a clang native
// vector type, not HIP_vector_type<float,4>. Use ext_vector_type(4).)
// Rationale: out (281.6 MB, never re-read) write-allocates in the 256 MB
// Infinity Cache and evicts the 281.6 MB feature table, capping the random
// gather hit rate at ~61% (FETCH 842 MB vs 293 MB compulsory). nt stores
// should leave L3 capacity to the feature table.

#define N_BUCKETS 11
#define BUCKET 50000
#define D 128
#define NTOT (N_BUCKETS * BUCKET)
#define ROWS_PER_BLOCK 8                     // 256 threads / 32 lanes-per-row
#define BLOCKS_PER_BUCKET (BUCKET / ROWS_PER_BLOCK)   // 6250

typedef float fvec4 __attribute__((ext_vector_type(4)));   // clang-native, nt-store-able

struct AdjPtrs {
    const int* p[N_BUCKETS];   // p[0] unused
};

template <int DEG>
__device__ __forceinline__ void pool_row(const float* __restrict__ feat,
                                         const int* __restrict__ adj,
                                         float* __restrict__ out,
                                         int local, int row, int lane) {
    // Each lane owns one float4 (16 B) of the 512 B row -> fully coalesced.
    const fvec4* __restrict__ f4 = (const fvec4*)feat;
    fvec4 acc = f4[row * 32 + lane];

    if (DEG > 0) {
        int idx[DEG > 0 ? DEG : 1];
        const int* __restrict__ a = adj + local * DEG;
#pragma unroll
        for (int j = 0; j < DEG; ++j)
            idx[j] = __builtin_nontemporal_load(a + j);  // read-once stream, don't cache
#pragma unroll
        for (int j = 0; j < DEG; ++j) {
            fvec4 v = f4[idx[j] * 32 + lane];           // independent gathers, issued together
            acc.x = fmaxf(acc.x, v.x);
            acc.y = fmaxf(acc.y, v.y);
            acc.z = fmaxf(acc.z, v.z);
            acc.w = fmaxf(acc.w, v.w);
        }
    }
    // Output is never re-read: bypass cache allocation (global_store_dwordx4 nt)
    __builtin_nontemporal_store(acc, (fvec4*)out + row * 32 + lane);
}

__global__ __launch_bounds__(256) void graphpool_kernel(
        const float* __restrict__ feat, AdjPtrs adj, float* __restrict__ out) {
    // deg = blockIdx % 11 interleaves heavy/light degree blocks across the grid
    // (load balance) and keeps deg block-uniform (each bucket = 6250 blocks).
    int deg  = blockIdx.x % N_BUCKETS;
    int lblk = blockIdx.x / N_BUCKETS;
    int r    = threadIdx.x >> 5;
    int lane = threadIdx.x & 31;
    int local = lblk * ROWS_PER_BLOCK + r;
    int row   = deg * BUCKET + local;    // deg_slice starts are statically deg*BUCKET

    switch (deg) {
        case 0:  pool_row<0 >(feat, nullptr,    out, local, row, lane); break;
        case 1:  pool_row<1 >(feat, adj.p[1],   out, local, row, lane); break;
        case 2:  pool_row<2 >(feat, adj.p[2],   out, local, row, lane); break;
        case 3:  pool_row<3 >(feat, adj.p[3],   out, local, row, lane); break;
        case 4:  pool_row<4 >(feat, adj.p[4],   out, local, row, lane); break;
        case 5:  pool_row<5 >(feat, adj.p[5],   out, local, row, lane); break;
        case 6:  pool_row<6 >(feat, adj.p[6],   out, local, row, lane); break;
        case 7:  pool_row<7 >(feat, adj.p[7],   out, local, row, lane); break;
        case 8:  pool_row<8 >(feat, adj.p[8],   out, local, row, lane); break;
        case 9:  pool_row<9 >(feat, adj.p[9],   out, local, row, lane); break;
        case 10: pool_row<10>(feat, adj.p[10],  out, local, row, lane); break;
    }
}

extern "C" void kernel_launch(void* const* d_in, const int* in_sizes, int n_in,
                              void* d_out, int out_size, void* d_ws, size_t ws_size,
                              hipStream_t stream) {
    const float* feat = (const float*)d_in[0];
    // d_in[1] = deg_slice (starts/counts are static: deg*50000 / 50000) -- unused.
    AdjPtrs adj;
    adj.p[0] = nullptr;
    for (int d = 1; d <= 10; ++d) adj.p[d] = (const int*)d_in[1 + d];
    float* out = (float*)d_out;

    dim3 grid(N_BUCKETS * BLOCKS_PER_BUCKET);   // 68750 blocks
    dim3 block(256);
    graphpool_kernel<<<grid, block, 0, stream>>>(feat, adj, out);
}